// Round 1
// baseline (906.801 us; speedup 1.0000x reference)
//
#include <hip/hip_runtime.h>
#include <hip/hip_bf16.h>
#include <hip/amd_detail/amd_hip_unsafe_atomics.h>

#define N_EDGES 200000
#define N_NODES 20000
#define N_GRAPHS 128
#define IN_DIM 16
#define EDGE_DIM 8
#define HID 64
#define OUT_DIM 10

// ---------------------------------------------------------------------------
// Kernel 0: fold emb into w3/b3 and root_w/conv_b.
//   W3p[k*64+h] = sum_i emb[i] * w3[k*1024 + i*64 + h]   (k,h in [0,64))
//   b3p[h]     = sum_i emb[i] * b3[i*64+h]
//   r[h]       = sum_i emb[i] * root_w[i*64+h] + conv_b[h]
// ---------------------------------------------------------------------------
__global__ __launch_bounds__(256) void precompute_kernel(
    const float* __restrict__ emb, const float* __restrict__ w3,
    const float* __restrict__ b3, const float* __restrict__ root_w,
    const float* __restrict__ conv_b,
    float* __restrict__ W3p, float* __restrict__ b3p, float* __restrict__ r)
{
    int t = blockIdx.x * 256 + threadIdx.x;   // 0..4095
    if (t >= HID * HID) return;
    int k = t >> 6;
    int h = t & 63;
    float acc = 0.f;
#pragma unroll
    for (int i = 0; i < IN_DIM; ++i)
        acc = fmaf(emb[i], w3[k * (IN_DIM * HID) + i * HID + h], acc);
    W3p[t] = acc;
    if (t < HID) {
        float a = 0.f, rr = 0.f;
#pragma unroll
        for (int i = 0; i < IN_DIM; ++i) {
            a  = fmaf(emb[i], b3[i * HID + t], a);
            rr = fmaf(emb[i], root_w[i * HID + t], rr);
        }
        b3p[t] = a;
        r[t]   = rr + conv_b[t];
    }
}

// ---------------------------------------------------------------------------
// Kernel 1: per-edge MLP + scatter-add.
//   h1 = relu(ea@w1+b1); h2 = relu(h1@w2+b2); msg = h2@W3p+b3p
//   agg[dst] += msg  (fp32 hw atomics)
// One thread per edge. Weights staged in LDS, read as broadcast float4.
// ---------------------------------------------------------------------------
__global__ __launch_bounds__(256) void edge_kernel(
    const float* __restrict__ edge_attr, const int* __restrict__ dst_idx,
    const float* __restrict__ w1, const float* __restrict__ b1,
    const float* __restrict__ w2, const float* __restrict__ b2,
    const float* __restrict__ W3p, const float* __restrict__ b3p,
    float* __restrict__ agg)
{
    __shared__ __align__(16) float s_w1[EDGE_DIM * HID];
    __shared__ __align__(16) float s_w2[HID * HID];
    __shared__ __align__(16) float s_w3[HID * HID];
    __shared__ __align__(16) float s_b1[HID];
    __shared__ __align__(16) float s_b2[HID];
    __shared__ __align__(16) float s_b3[HID];

    for (int i = threadIdx.x; i < EDGE_DIM * HID; i += 256) s_w1[i] = w1[i];
    for (int i = threadIdx.x; i < HID * HID; i += 256) s_w2[i] = w2[i];
    for (int i = threadIdx.x; i < HID * HID; i += 256) s_w3[i] = W3p[i];
    if (threadIdx.x < HID) {
        s_b1[threadIdx.x] = b1[threadIdx.x];
        s_b2[threadIdx.x] = b2[threadIdx.x];
        s_b3[threadIdx.x] = b3p[threadIdx.x];
    }
    __syncthreads();

    int e = blockIdx.x * 256 + threadIdx.x;
    if (e >= N_EDGES) return;

    // load edge attrs (32B contiguous per thread -> coalesced dwordx4 x2)
    float ea[EDGE_DIM];
    {
        const float4 a0 = *(const float4*)&edge_attr[e * EDGE_DIM + 0];
        const float4 a1 = *(const float4*)&edge_attr[e * EDGE_DIM + 4];
        ea[0] = a0.x; ea[1] = a0.y; ea[2] = a0.z; ea[3] = a0.w;
        ea[4] = a1.x; ea[5] = a1.y; ea[6] = a1.z; ea[7] = a1.w;
    }

    // ---- h1 = relu(ea @ w1 + b1) ----
    float h1[HID];
#pragma unroll
    for (int jc = 0; jc < HID / 4; ++jc) {
        float4 acc = *(const float4*)&s_b1[jc * 4];
#pragma unroll
        for (int i = 0; i < EDGE_DIM; ++i) {
            const float4 w = *(const float4*)&s_w1[i * HID + jc * 4];
            acc.x = fmaf(ea[i], w.x, acc.x);
            acc.y = fmaf(ea[i], w.y, acc.y);
            acc.z = fmaf(ea[i], w.z, acc.z);
            acc.w = fmaf(ea[i], w.w, acc.w);
        }
        h1[jc * 4 + 0] = fmaxf(acc.x, 0.f);
        h1[jc * 4 + 1] = fmaxf(acc.y, 0.f);
        h1[jc * 4 + 2] = fmaxf(acc.z, 0.f);
        h1[jc * 4 + 3] = fmaxf(acc.w, 0.f);
    }

    // ---- h2 = relu(h1 @ w2 + b2) ----
    float h2[HID];
#pragma unroll
    for (int jc = 0; jc < HID / 4; ++jc) {
        float4 acc = *(const float4*)&s_b2[jc * 4];
#pragma unroll
        for (int k = 0; k < HID; ++k) {
            const float4 w = *(const float4*)&s_w2[k * HID + jc * 4];
            acc.x = fmaf(h1[k], w.x, acc.x);
            acc.y = fmaf(h1[k], w.y, acc.y);
            acc.z = fmaf(h1[k], w.z, acc.z);
            acc.w = fmaf(h1[k], w.w, acc.w);
        }
        h2[jc * 4 + 0] = fmaxf(acc.x, 0.f);
        h2[jc * 4 + 1] = fmaxf(acc.y, 0.f);
        h2[jc * 4 + 2] = fmaxf(acc.z, 0.f);
        h2[jc * 4 + 3] = fmaxf(acc.w, 0.f);
    }

    // ---- msg = h2 @ W3p + b3p  (no relu) ----
    float msg[HID];
#pragma unroll
    for (int jc = 0; jc < HID / 4; ++jc) {
        float4 acc = *(const float4*)&s_b3[jc * 4];
#pragma unroll
        for (int k = 0; k < HID; ++k) {
            const float4 w = *(const float4*)&s_w3[k * HID + jc * 4];
            acc.x = fmaf(h2[k], w.x, acc.x);
            acc.y = fmaf(h2[k], w.y, acc.y);
            acc.z = fmaf(h2[k], w.z, acc.z);
            acc.w = fmaf(h2[k], w.w, acc.w);
        }
        msg[jc * 4 + 0] = acc.x;
        msg[jc * 4 + 1] = acc.y;
        msg[jc * 4 + 2] = acc.z;
        msg[jc * 4 + 3] = acc.w;
    }

    // ---- scatter-add into agg[dst] ----
    const int d = dst_idx[e];
    float* dest = agg + (long)d * HID;
#pragma unroll
    for (int j = 0; j < HID; ++j)
        unsafeAtomicAdd(dest + j, msg[j]);
}

// ---------------------------------------------------------------------------
// Kernel 2: out = relu(agg + r), pooled-sum per graph (batch is sorted, so
// each wave locally accumulates runs of equal graph id before one atomic).
// One wave (64 threads = 64 hid channels) per 128-node chunk.
// ---------------------------------------------------------------------------
#define NODES_PER_BLOCK 128
__global__ __launch_bounds__(64) void node_kernel(
    const float* __restrict__ agg, const float* __restrict__ r,
    const int* __restrict__ batch,
    float* __restrict__ sums, float* __restrict__ counts)
{
    const int j  = threadIdx.x;           // hid channel
    const int n0 = blockIdx.x * NODES_PER_BLOCK;
    const int n1 = min(n0 + NODES_PER_BLOCK, N_NODES);
    if (n0 >= N_NODES) return;
    const float rj = r[j];

    int   g   = batch[n0];
    float acc = 0.f;
    float cnt = 0.f;
    for (int n = n0; n < n1; ++n) {
        const int gn = batch[n];          // wave-uniform -> s_load
        if (gn != g) {
            unsafeAtomicAdd(&sums[g * HID + j], acc);
            if (j == 0) unsafeAtomicAdd(&counts[g], cnt);
            g = gn; acc = 0.f; cnt = 0.f;
        }
        acc += fmaxf(agg[(long)n * HID + j] + rj, 0.f);
        cnt += 1.f;
    }
    unsafeAtomicAdd(&sums[g * HID + j], acc);
    if (j == 0) unsafeAtomicAdd(&counts[g], cnt);
}

// ---------------------------------------------------------------------------
// Kernel 3: classifier head. One block (128 threads) per graph.
//   pooled = sums/count; hid = relu(pooled@l1_w+l1_b); out = hid@l2_w+l2_b
// ---------------------------------------------------------------------------
__global__ __launch_bounds__(128) void head_kernel(
    const float* __restrict__ sums, const float* __restrict__ counts,
    const float* __restrict__ l1_w, const float* __restrict__ l1_b,
    const float* __restrict__ l2_w, const float* __restrict__ l2_b,
    float* __restrict__ out)
{
    const int g = blockIdx.x;
    const int t = threadIdx.x;
    __shared__ float pooled[HID];
    __shared__ float hid[2 * HID];

    const float cnt = fmaxf(counts[g], 1.0f);
    if (t < HID) pooled[t] = sums[g * HID + t] / cnt;
    __syncthreads();

    float a = l1_b[t];
#pragma unroll
    for (int k = 0; k < HID; ++k)
        a = fmaf(pooled[k], l1_w[k * (2 * HID) + t], a);
    hid[t] = fmaxf(a, 0.f);
    __syncthreads();

    if (t < OUT_DIM) {
        float o = l2_b[t];
#pragma unroll
        for (int k = 0; k < 2 * HID; ++k)
            o = fmaf(hid[k], l2_w[k * OUT_DIM + t], o);
        out[g * OUT_DIM + t] = o;
    }
}

// ---------------------------------------------------------------------------
extern "C" void kernel_launch(void* const* d_in, const int* in_sizes, int n_in,
                              void* d_out, int out_size, void* d_ws, size_t ws_size,
                              hipStream_t stream) {
    const float* edge_attr = (const float*)d_in[0];
    const int*   edge_idx  = (const int*)d_in[1];
    const int*   batch     = (const int*)d_in[2];
    const float* node_emb  = (const float*)d_in[3];
    const float* w1        = (const float*)d_in[4];
    const float* b1        = (const float*)d_in[5];
    const float* w2        = (const float*)d_in[6];
    const float* b2        = (const float*)d_in[7];
    const float* w3        = (const float*)d_in[8];
    const float* b3        = (const float*)d_in[9];
    const float* root_w    = (const float*)d_in[10];
    const float* conv_b    = (const float*)d_in[11];
    const float* l1_w      = (const float*)d_in[12];
    const float* l1_b      = (const float*)d_in[13];
    const float* l2_w      = (const float*)d_in[14];
    const float* l2_b      = (const float*)d_in[15];
    float* out = (float*)d_out;

    // workspace layout (floats)
    float* ws    = (float*)d_ws;
    float* W3p   = ws;                         // 4096
    float* b3p   = W3p + HID * HID;            // 64
    float* r     = b3p + HID;                  // 64
    float* sums  = r + HID;                    // 128*64 = 8192
    float* cts   = sums + N_GRAPHS * HID;      // 128
    float* agg   = cts + N_GRAPHS;             // 20000*64 = 1,280,000
    const size_t total_f = (size_t)(agg - ws) + (size_t)N_NODES * HID;

    // zero the accumulators (covers everything; precompute overwrites its part)
    hipMemsetAsync(d_ws, 0, total_f * sizeof(float), stream);

    precompute_kernel<<<(HID * HID + 255) / 256, 256, 0, stream>>>(
        node_emb, w3, b3, root_w, conv_b, W3p, b3p, r);

    const int* dst_idx = edge_idx + N_EDGES;   // edge_index[1]
    edge_kernel<<<(N_EDGES + 255) / 256, 256, 0, stream>>>(
        edge_attr, dst_idx, w1, b1, w2, b2, W3p, b3p, agg);

    node_kernel<<<(N_NODES + NODES_PER_BLOCK - 1) / NODES_PER_BLOCK, 64, 0, stream>>>(
        agg, r, batch, sums, cts);

    head_kernel<<<N_GRAPHS, 128, 0, stream>>>(
        sums, cts, l1_w, l1_b, l2_w, l2_b, out);
}

// Round 2
// 342.069 us; speedup vs baseline: 2.6509x; 2.6509x over previous
//
#include <hip/hip_runtime.h>
#include <hip/hip_bf16.h>
#include <hip/amd_detail/amd_hip_unsafe_atomics.h>

#define N_EDGES 200000
#define N_NODES 20000
#define N_GRAPHS 128
#define IN_DIM 16
#define EDGE_DIM 8
#define HID 64
#define OUT_DIM 10

// ---------------------------------------------------------------------------
// Kernel 0: fold emb into w3/b3 and root_w/conv_b.
// ---------------------------------------------------------------------------
__global__ __launch_bounds__(256) void precompute_kernel(
    const float* __restrict__ emb, const float* __restrict__ w3,
    const float* __restrict__ b3, const float* __restrict__ root_w,
    const float* __restrict__ conv_b,
    float* __restrict__ W3p, float* __restrict__ b3p, float* __restrict__ r)
{
    int t = blockIdx.x * 256 + threadIdx.x;   // 0..4095
    if (t >= HID * HID) return;
    int k = t >> 6;
    int h = t & 63;
    float acc = 0.f;
#pragma unroll
    for (int i = 0; i < IN_DIM; ++i)
        acc = fmaf(emb[i], w3[k * (IN_DIM * HID) + i * HID + h], acc);
    W3p[t] = acc;
    if (t < HID) {
        float a = 0.f, rr = 0.f;
#pragma unroll
        for (int i = 0; i < IN_DIM; ++i) {
            a  = fmaf(emb[i], b3[i * HID + t], a);
            rr = fmaf(emb[i], root_w[i * HID + t], rr);
        }
        b3p[t] = a;
        r[t]   = rr + conv_b[t];
    }
}

// ---------------------------------------------------------------------------
// Kernel 1: histogram of destination indices.
// ---------------------------------------------------------------------------
__global__ __launch_bounds__(256) void hist_kernel(
    const int* __restrict__ dst_idx, int* __restrict__ counts)
{
    int e = blockIdx.x * 256 + threadIdx.x;
    if (e < N_EDGES) atomicAdd(&counts[dst_idx[e]], 1);
}

// ---------------------------------------------------------------------------
// Kernel 2: exclusive prefix scan of counts -> start[] and cursor[].
// Single block, 1024 threads, Hillis-Steele per 1024-chunk with carry.
// ---------------------------------------------------------------------------
__global__ __launch_bounds__(1024) void scan_kernel(
    const int* __restrict__ counts, int* __restrict__ start,
    int* __restrict__ cursor)
{
    __shared__ int s[1024];
    __shared__ int s_carry;
    const int t = threadIdx.x;
    if (t == 0) s_carry = 0;
    __syncthreads();
    for (int base = 0; base < N_NODES; base += 1024) {
        const int i = base + t;
        const int v = (i < N_NODES) ? counts[i] : 0;
        s[t] = v;
        __syncthreads();
        for (int off = 1; off < 1024; off <<= 1) {
            int add = (t >= off) ? s[t - off] : 0;
            __syncthreads();
            s[t] += add;
            __syncthreads();
        }
        const int incl  = s[t];
        const int excl  = incl - v;
        const int carry = s_carry;
        if (i < N_NODES) {
            start[i]  = carry + excl;
            cursor[i] = carry + excl;
        }
        __syncthreads();
        if (t == 1023) s_carry = carry + incl;
        __syncthreads();
    }
    if (t == 0) start[N_NODES] = N_EDGES;
}

// ---------------------------------------------------------------------------
// Kernel 3: per-edge MLP; write msg row into dst-sorted slot (no fp atomics).
// ---------------------------------------------------------------------------
__global__ __launch_bounds__(256) void edge_kernel(
    const float* __restrict__ edge_attr, const int* __restrict__ dst_idx,
    const float* __restrict__ w1, const float* __restrict__ b1,
    const float* __restrict__ w2, const float* __restrict__ b2,
    const float* __restrict__ W3p, const float* __restrict__ b3p,
    int* __restrict__ cursor, float* __restrict__ msg_buf)
{
    __shared__ __align__(16) float s_w1[EDGE_DIM * HID];
    __shared__ __align__(16) float s_w2[HID * HID];
    __shared__ __align__(16) float s_w3[HID * HID];
    __shared__ __align__(16) float s_b1[HID];
    __shared__ __align__(16) float s_b2[HID];
    __shared__ __align__(16) float s_b3[HID];

    for (int i = threadIdx.x; i < EDGE_DIM * HID; i += 256) s_w1[i] = w1[i];
    for (int i = threadIdx.x; i < HID * HID; i += 256) s_w2[i] = w2[i];
    for (int i = threadIdx.x; i < HID * HID; i += 256) s_w3[i] = W3p[i];
    if (threadIdx.x < HID) {
        s_b1[threadIdx.x] = b1[threadIdx.x];
        s_b2[threadIdx.x] = b2[threadIdx.x];
        s_b3[threadIdx.x] = b3p[threadIdx.x];
    }
    __syncthreads();

    const int e = blockIdx.x * 256 + threadIdx.x;
    if (e >= N_EDGES) return;

    float ea[EDGE_DIM];
    {
        const float4 a0 = *(const float4*)&edge_attr[e * EDGE_DIM + 0];
        const float4 a1 = *(const float4*)&edge_attr[e * EDGE_DIM + 4];
        ea[0] = a0.x; ea[1] = a0.y; ea[2] = a0.z; ea[3] = a0.w;
        ea[4] = a1.x; ea[5] = a1.y; ea[6] = a1.z; ea[7] = a1.w;
    }

    // ---- h1 = relu(ea @ w1 + b1) ----
    float h1[HID];
#pragma unroll
    for (int jc = 0; jc < HID / 4; ++jc) {
        float4 acc = *(const float4*)&s_b1[jc * 4];
#pragma unroll
        for (int i = 0; i < EDGE_DIM; ++i) {
            const float4 w = *(const float4*)&s_w1[i * HID + jc * 4];
            acc.x = fmaf(ea[i], w.x, acc.x);
            acc.y = fmaf(ea[i], w.y, acc.y);
            acc.z = fmaf(ea[i], w.z, acc.z);
            acc.w = fmaf(ea[i], w.w, acc.w);
        }
        h1[jc * 4 + 0] = fmaxf(acc.x, 0.f);
        h1[jc * 4 + 1] = fmaxf(acc.y, 0.f);
        h1[jc * 4 + 2] = fmaxf(acc.z, 0.f);
        h1[jc * 4 + 3] = fmaxf(acc.w, 0.f);
    }

    // ---- h2 = relu(h1 @ w2 + b2) ----
    float h2[HID];
#pragma unroll
    for (int jc = 0; jc < HID / 4; ++jc) {
        float4 acc = *(const float4*)&s_b2[jc * 4];
#pragma unroll
        for (int k = 0; k < HID; ++k) {
            const float4 w = *(const float4*)&s_w2[k * HID + jc * 4];
            acc.x = fmaf(h1[k], w.x, acc.x);
            acc.y = fmaf(h1[k], w.y, acc.y);
            acc.z = fmaf(h1[k], w.z, acc.z);
            acc.w = fmaf(h1[k], w.w, acc.w);
        }
        h2[jc * 4 + 0] = fmaxf(acc.x, 0.f);
        h2[jc * 4 + 1] = fmaxf(acc.y, 0.f);
        h2[jc * 4 + 2] = fmaxf(acc.z, 0.f);
        h2[jc * 4 + 3] = fmaxf(acc.w, 0.f);
    }

    // ---- msg = h2 @ W3p + b3p ----
    float4 msg4[HID / 4];
#pragma unroll
    for (int jc = 0; jc < HID / 4; ++jc) {
        float4 acc = *(const float4*)&s_b3[jc * 4];
#pragma unroll
        for (int k = 0; k < HID; ++k) {
            const float4 w = *(const float4*)&s_w3[k * HID + jc * 4];
            acc.x = fmaf(h2[k], w.x, acc.x);
            acc.y = fmaf(h2[k], w.y, acc.y);
            acc.z = fmaf(h2[k], w.z, acc.z);
            acc.w = fmaf(h2[k], w.w, acc.w);
        }
        msg4[jc] = acc;
    }

    // ---- write into dst-sorted slot ----
    const int d = dst_idx[e];
    const int p = atomicAdd(&cursor[d], 1);
    float* dest = msg_buf + (long)p * HID;
#pragma unroll
    for (int jc = 0; jc < HID / 4; ++jc)
        *(float4*)&dest[jc * 4] = msg4[jc];
}

// ---------------------------------------------------------------------------
// Kernel 4: gather msg rows per node, +r, relu, per-graph pooled sums/counts.
// One wave per 8 nodes; lane = hid channel; batch sorted -> run accumulation.
// ---------------------------------------------------------------------------
#define GN_PER_WAVE 8
__global__ __launch_bounds__(256) void gather_kernel(
    const float* __restrict__ msg_buf, const int* __restrict__ start,
    const float* __restrict__ r, const int* __restrict__ batch,
    float* __restrict__ sums, float* __restrict__ counts_f)
{
    const int wave = threadIdx.x >> 6;
    const int j    = threadIdx.x & 63;
    const int n0   = blockIdx.x * (4 * GN_PER_WAVE) + wave * GN_PER_WAVE;
    if (n0 >= N_NODES) return;
    const int n1 = min(n0 + GN_PER_WAVE, N_NODES);
    const float rj = r[j];

    int   g    = batch[n0];
    float pacc = 0.f, cnt = 0.f;
    for (int n = n0; n < n1; ++n) {
        const int gn = batch[n];
        if (gn != g) {
            unsafeAtomicAdd(&sums[g * HID + j], pacc);
            if (j == 0) unsafeAtomicAdd(&counts_f[g], cnt);
            g = gn; pacc = 0.f; cnt = 0.f;
        }
        float acc = 0.f;
        const int p0 = start[n], p1 = start[n + 1];
        for (int p = p0; p < p1; ++p)
            acc += msg_buf[(long)p * HID + j];
        pacc += fmaxf(acc + rj, 0.f);
        cnt  += 1.f;
    }
    unsafeAtomicAdd(&sums[g * HID + j], pacc);
    if (j == 0) unsafeAtomicAdd(&counts_f[g], cnt);
}

// ---------------------------------------------------------------------------
// Kernel 5: classifier head. One block (128 threads) per graph.
// ---------------------------------------------------------------------------
__global__ __launch_bounds__(128) void head_kernel(
    const float* __restrict__ sums, const float* __restrict__ counts,
    const float* __restrict__ l1_w, const float* __restrict__ l1_b,
    const float* __restrict__ l2_w, const float* __restrict__ l2_b,
    float* __restrict__ out)
{
    const int g = blockIdx.x;
    const int t = threadIdx.x;
    __shared__ float pooled[HID];
    __shared__ float hid[2 * HID];

    const float cnt = fmaxf(counts[g], 1.0f);
    if (t < HID) pooled[t] = sums[g * HID + t] / cnt;
    __syncthreads();

    float a = l1_b[t];
#pragma unroll
    for (int k = 0; k < HID; ++k)
        a = fmaf(pooled[k], l1_w[k * (2 * HID) + t], a);
    hid[t] = fmaxf(a, 0.f);
    __syncthreads();

    if (t < OUT_DIM) {
        float o = l2_b[t];
#pragma unroll
        for (int k = 0; k < 2 * HID; ++k)
            o = fmaf(hid[k], l2_w[k * OUT_DIM + t], o);
        out[g * OUT_DIM + t] = o;
    }
}

// ---------------------------------------------------------------------------
extern "C" void kernel_launch(void* const* d_in, const int* in_sizes, int n_in,
                              void* d_out, int out_size, void* d_ws, size_t ws_size,
                              hipStream_t stream) {
    const float* edge_attr = (const float*)d_in[0];
    const int*   edge_idx  = (const int*)d_in[1];
    const int*   batch     = (const int*)d_in[2];
    const float* node_emb  = (const float*)d_in[3];
    const float* w1        = (const float*)d_in[4];
    const float* b1        = (const float*)d_in[5];
    const float* w2        = (const float*)d_in[6];
    const float* b2        = (const float*)d_in[7];
    const float* w3        = (const float*)d_in[8];
    const float* b3        = (const float*)d_in[9];
    const float* root_w    = (const float*)d_in[10];
    const float* conv_b    = (const float*)d_in[11];
    const float* l1_w      = (const float*)d_in[12];
    const float* l1_b      = (const float*)d_in[13];
    const float* l2_w      = (const float*)d_in[14];
    const float* l2_b      = (const float*)d_in[15];
    float* out = (float*)d_out;

    // workspace layout
    float* ws     = (float*)d_ws;
    float* W3p    = ws;                          // 4096
    float* b3p    = W3p + HID * HID;             // 64
    float* r      = b3p + HID;                   // 64
    float* sums   = r + HID;                     // 128*64
    float* cts    = sums + N_GRAPHS * HID;       // 128
    int*   counts = (int*)(cts + N_GRAPHS);      // 20000
    int*   startp = counts + N_NODES;            // 20001
    int*   cursor = startp + (N_NODES + 1);      // 20000
    float* msg    = (float*)(cursor + N_NODES);  // 200000*64 floats (51.2 MB)

    // zero sums/cts/counts (contiguous region)
    hipMemsetAsync(sums, 0,
                   (size_t)(N_GRAPHS * HID + N_GRAPHS + N_NODES) * 4, stream);

    precompute_kernel<<<(HID * HID + 255) / 256, 256, 0, stream>>>(
        node_emb, w3, b3, root_w, conv_b, W3p, b3p, r);

    const int* dst_idx = edge_idx + N_EDGES;   // edge_index[1]

    hist_kernel<<<(N_EDGES + 255) / 256, 256, 0, stream>>>(dst_idx, counts);

    scan_kernel<<<1, 1024, 0, stream>>>(counts, startp, cursor);

    edge_kernel<<<(N_EDGES + 255) / 256, 256, 0, stream>>>(
        edge_attr, dst_idx, w1, b1, w2, b2, W3p, b3p, cursor, msg);

    gather_kernel<<<(N_NODES + 4 * GN_PER_WAVE - 1) / (4 * GN_PER_WAVE), 256, 0, stream>>>(
        msg, startp, r, batch, sums, cts);

    head_kernel<<<N_GRAPHS, 128, 0, stream>>>(
        sums, cts, l1_w, l1_b, l2_w, l2_b, out);
}

// Round 5
// 244.638 us; speedup vs baseline: 3.7067x; 1.3983x over previous
//
#include <hip/hip_runtime.h>
#include <hip/hip_bf16.h>
#include <hip/amd_detail/amd_hip_unsafe_atomics.h>

#define N_EDGES 200000
#define N_NODES 20000
#define N_GRAPHS 128
#define IN_DIM 16
#define EDGE_DIM 8
#define HID 64
#define OUT_DIM 10

// ---------------------------------------------------------------------------
// Kernel 0: fold emb into w3/b3 and root_w/conv_b.
// ---------------------------------------------------------------------------
__global__ __launch_bounds__(256) void precompute_kernel(
    const float* __restrict__ emb, const float* __restrict__ w3,
    const float* __restrict__ b3, const float* __restrict__ root_w,
    const float* __restrict__ conv_b,
    float* __restrict__ W3p, float* __restrict__ b3p, float* __restrict__ r)
{
    int t = blockIdx.x * 256 + threadIdx.x;   // 0..4095
    if (t >= HID * HID) return;
    int k = t >> 6;
    int h = t & 63;
    float acc = 0.f;
#pragma unroll
    for (int i = 0; i < IN_DIM; ++i)
        acc = fmaf(emb[i], w3[k * (IN_DIM * HID) + i * HID + h], acc);
    W3p[t] = acc;
    if (t < HID) {
        float a = 0.f, rr = 0.f;
#pragma unroll
        for (int i = 0; i < IN_DIM; ++i) {
            a  = fmaf(emb[i], b3[i * HID + t], a);
            rr = fmaf(emb[i], root_w[i * HID + t], rr);
        }
        b3p[t] = a;
        r[t]   = rr + conv_b[t];
    }
}

// ---------------------------------------------------------------------------
// Kernel 1: histogram of destination indices.
// ---------------------------------------------------------------------------
__global__ __launch_bounds__(256) void hist_kernel(
    const int* __restrict__ dst_idx, int* __restrict__ counts)
{
    int e = blockIdx.x * 256 + threadIdx.x;
    if (e < N_EDGES) atomicAdd(&counts[dst_idx[e]], 1);
}

// ---------------------------------------------------------------------------
// Kernel 2: exclusive prefix scan of counts -> start[] and cursor[].
// Single block, 1024 threads. Wave-level shfl scan (no LDS Hillis-Steele).
// ---------------------------------------------------------------------------
__global__ __launch_bounds__(1024) void scan_kernel(
    const int* __restrict__ counts, int* __restrict__ start,
    int* __restrict__ cursor)
{
    __shared__ int s_wsum[16];
    __shared__ int s_carry;
    const int t    = threadIdx.x;
    const int lane = t & 63;
    const int wid  = t >> 6;
    if (t == 0) s_carry = 0;
    __syncthreads();
    for (int base = 0; base < N_NODES; base += 1024) {
        const int i = base + t;
        const int v = (i < N_NODES) ? counts[i] : 0;
        int incl = v;
#pragma unroll
        for (int off = 1; off < 64; off <<= 1) {
            int u = __shfl_up(incl, off, 64);
            if (lane >= off) incl += u;
        }
        if (lane == 63) s_wsum[wid] = incl;
        __syncthreads();
        if (wid == 0) {
            int wv = (lane < 16) ? s_wsum[lane] : 0;
            int wi = wv;
#pragma unroll
            for (int off = 1; off < 16; off <<= 1) {
                int u = __shfl_up(wi, off, 64);
                if (lane >= off) wi += u;
            }
            if (lane < 16) s_wsum[lane] = wi - wv;   // exclusive wave prefix
        }
        __syncthreads();
        const int carry = s_carry;
        const int excl  = carry + s_wsum[wid] + incl - v;
        if (i < N_NODES) { start[i] = excl; cursor[i] = excl; }
        __syncthreads();
        if (t == 1023) s_carry = excl + v;
        __syncthreads();
    }
    if (t == 0) start[N_NODES] = N_EDGES;
}

// ---------------------------------------------------------------------------
// Kernel 3: per-edge MLP; weights read via wave-uniform (scalar) loads, all
// activations in registers with compile-time indices (full unroll).
// Writes msg row into dst-sorted slot (no fp atomics).
// ---------------------------------------------------------------------------
__global__ __launch_bounds__(256) void edge_kernel(
    const float* __restrict__ edge_attr, const int* __restrict__ dst_idx,
    const float* __restrict__ w1, const float* __restrict__ b1,
    const float* __restrict__ w2, const float* __restrict__ b2,
    const float* __restrict__ W3p, const float* __restrict__ b3p,
    int* __restrict__ cursor, float* __restrict__ msg_buf)
{
    const int e = blockIdx.x * 256 + threadIdx.x;
    if (e >= N_EDGES) return;

    float ea[EDGE_DIM];
    {
        const float4 a0 = *(const float4*)&edge_attr[e * EDGE_DIM + 0];
        const float4 a1 = *(const float4*)&edge_attr[e * EDGE_DIM + 4];
        ea[0] = a0.x; ea[1] = a0.y; ea[2] = a0.z; ea[3] = a0.w;
        ea[4] = a1.x; ea[5] = a1.y; ea[6] = a1.z; ea[7] = a1.w;
    }

    float acc[HID];
    float h[HID];

    // ---- L1: h = relu(ea @ w1 + b1) ----
#pragma unroll
    for (int j = 0; j < HID; ++j) acc[j] = b1[j];
#pragma unroll
    for (int k = 0; k < EDGE_DIM; ++k) {
        const float x = ea[k];
        const float* __restrict__ row = w1 + k * HID;
#pragma unroll
        for (int j = 0; j < HID; ++j) acc[j] = fmaf(x, row[j], acc[j]);
    }
#pragma unroll
    for (int j = 0; j < HID; ++j) h[j] = fmaxf(acc[j], 0.f);

    // ---- L2: h = relu(h @ w2 + b2) ----
#pragma unroll
    for (int j = 0; j < HID; ++j) acc[j] = b2[j];
#pragma unroll
    for (int k = 0; k < HID; ++k) {
        const float x = h[k];
        const float* __restrict__ row = w2 + k * HID;
#pragma unroll
        for (int j = 0; j < HID; ++j) acc[j] = fmaf(x, row[j], acc[j]);
    }
#pragma unroll
    for (int j = 0; j < HID; ++j) h[j] = fmaxf(acc[j], 0.f);

    // ---- L3: msg = h @ W3p + b3p ----
#pragma unroll
    for (int j = 0; j < HID; ++j) acc[j] = b3p[j];
#pragma unroll
    for (int k = 0; k < HID; ++k) {
        const float x = h[k];
        const float* __restrict__ row = W3p + k * HID;
#pragma unroll
        for (int j = 0; j < HID; ++j) acc[j] = fmaf(x, row[j], acc[j]);
    }

    // ---- write into dst-sorted slot ----
    const int d = dst_idx[e];
    const int p = atomicAdd(&cursor[d], 1);
    float* dest = msg_buf + (long)p * HID;
#pragma unroll
    for (int jc = 0; jc < HID / 4; ++jc) {
        float4 v;
        v.x = acc[jc * 4 + 0];
        v.y = acc[jc * 4 + 1];
        v.z = acc[jc * 4 + 2];
        v.w = acc[jc * 4 + 3];
        *(float4*)&dest[jc * 4] = v;
    }
}

// ---------------------------------------------------------------------------
// Kernel 4: gather msg rows per node, +r, relu, per-graph pooled sums/counts.
// One wave per 8 nodes; lane = hid channel; batch sorted -> run accumulation.
// ---------------------------------------------------------------------------
#define GN_PER_WAVE 8
__global__ __launch_bounds__(256) void gather_kernel(
    const float* __restrict__ msg_buf, const int* __restrict__ start,
    const float* __restrict__ r, const int* __restrict__ batch,
    float* __restrict__ sums, float* __restrict__ counts_f)
{
    const int wave = threadIdx.x >> 6;
    const int j    = threadIdx.x & 63;
    const int n0   = blockIdx.x * (4 * GN_PER_WAVE) + wave * GN_PER_WAVE;
    if (n0 >= N_NODES) return;
    const int n1 = min(n0 + GN_PER_WAVE, N_NODES);
    const float rj = r[j];

    int   g    = batch[n0];
    float pacc = 0.f, cnt = 0.f;
    for (int n = n0; n < n1; ++n) {
        const int gn = batch[n];
        if (gn != g) {
            unsafeAtomicAdd(&sums[g * HID + j], pacc);
            if (j == 0) unsafeAtomicAdd(&counts_f[g], cnt);
            g = gn; pacc = 0.f; cnt = 0.f;
        }
        float acc = 0.f;
        const int p0 = start[n], p1 = start[n + 1];
        for (int p = p0; p < p1; ++p)
            acc += msg_buf[(long)p * HID + j];
        pacc += fmaxf(acc + rj, 0.f);
        cnt  += 1.f;
    }
    unsafeAtomicAdd(&sums[g * HID + j], pacc);
    if (j == 0) unsafeAtomicAdd(&counts_f[g], cnt);
}

// ---------------------------------------------------------------------------
// Kernel 5: classifier head. One block (128 threads) per graph.
// ---------------------------------------------------------------------------
__global__ __launch_bounds__(128) void head_kernel(
    const float* __restrict__ sums, const float* __restrict__ counts,
    const float* __restrict__ l1_w, const float* __restrict__ l1_b,
    const float* __restrict__ l2_w, const float* __restrict__ l2_b,
    float* __restrict__ out)
{
    const int g = blockIdx.x;
    const int t = threadIdx.x;
    __shared__ float pooled[HID];
    __shared__ float hid[2 * HID];

    const float cnt = fmaxf(counts[g], 1.0f);
    if (t < HID) pooled[t] = sums[g * HID + t] / cnt;
    __syncthreads();

    float a = l1_b[t];
#pragma unroll
    for (int k = 0; k < HID; ++k)
        a = fmaf(pooled[k], l1_w[k * (2 * HID) + t], a);
    hid[t] = fmaxf(a, 0.f);
    __syncthreads();

    if (t < OUT_DIM) {
        float o = l2_b[t];
#pragma unroll
        for (int k = 0; k < 2 * HID; ++k)
            o = fmaf(hid[k], l2_w[k * OUT_DIM + t], o);
        out[g * OUT_DIM + t] = o;
    }
}

// ---------------------------------------------------------------------------
extern "C" void kernel_launch(void* const* d_in, const int* in_sizes, int n_in,
                              void* d_out, int out_size, void* d_ws, size_t ws_size,
                              hipStream_t stream) {
    const float* edge_attr = (const float*)d_in[0];
    const int*   edge_idx  = (const int*)d_in[1];
    const int*   batch     = (const int*)d_in[2];
    const float* node_emb  = (const float*)d_in[3];
    const float* w1        = (const float*)d_in[4];
    const float* b1        = (const float*)d_in[5];
    const float* w2        = (const float*)d_in[6];
    const float* b2        = (const float*)d_in[7];
    const float* w3        = (const float*)d_in[8];
    const float* b3        = (const float*)d_in[9];
    const float* root_w    = (const float*)d_in[10];
    const float* conv_b    = (const float*)d_in[11];
    const float* l1_w      = (const float*)d_in[12];
    const float* l1_b      = (const float*)d_in[13];
    const float* l2_w      = (const float*)d_in[14];
    const float* l2_b      = (const float*)d_in[15];
    float* out = (float*)d_out;

    // workspace layout
    float* ws     = (float*)d_ws;
    float* W3p    = ws;                          // 4096
    float* b3p    = W3p + HID * HID;             // 64
    float* r      = b3p + HID;                   // 64
    float* sums   = r + HID;                     // 128*64
    float* cts    = sums + N_GRAPHS * HID;       // 128
    int*   counts = (int*)(cts + N_GRAPHS);      // 20000
    int*   startp = counts + N_NODES;            // 20001
    int*   cursor = startp + (N_NODES + 1);      // 20000
    float* msg    = (float*)(cursor + N_NODES);  // 200000*64 floats (51.2 MB)

    // zero sums/cts/counts (contiguous region)
    hipMemsetAsync(sums, 0,
                   (size_t)(N_GRAPHS * HID + N_GRAPHS + N_NODES) * 4, stream);

    precompute_kernel<<<(HID * HID + 255) / 256, 256, 0, stream>>>(
        node_emb, w3, b3, root_w, conv_b, W3p, b3p, r);

    const int* dst_idx = edge_idx + N_EDGES;   // edge_index[1]

    hist_kernel<<<(N_EDGES + 255) / 256, 256, 0, stream>>>(dst_idx, counts);

    scan_kernel<<<1, 1024, 0, stream>>>(counts, startp, cursor);

    edge_kernel<<<(N_EDGES + 255) / 256, 256, 0, stream>>>(
        edge_attr, dst_idx, w1, b1, w2, b2, W3p, b3p, cursor, msg);

    gather_kernel<<<(N_NODES + 4 * GN_PER_WAVE - 1) / (4 * GN_PER_WAVE), 256, 0, stream>>>(
        msg, startp, r, batch, sums, cts);

    head_kernel<<<N_GRAPHS, 128, 0, stream>>>(
        sums, cts, l1_w, l1_b, l2_w, l2_b, out);
}

// Round 7
// 202.736 us; speedup vs baseline: 4.4728x; 1.2067x over previous
//
#include <hip/hip_runtime.h>
#include <hip/hip_bf16.h>
#include <hip/amd_detail/amd_hip_unsafe_atomics.h>

#define N_EDGES 200000
#define N_NODES 20000
#define N_GRAPHS 128
#define IN_DIM 16
#define EDGE_DIM 8
#define HID 64
#define OUT_DIM 10
#define SCAN_NBLK ((N_NODES + 1023) / 1024)   // 20

__device__ __forceinline__ float rlanef(float v, int l) {
    return __int_as_float(__builtin_amdgcn_readlane(__float_as_int(v), l));
}

// ---------------------------------------------------------------------------
// Kernel 0: fold emb into w3/b3 and root_w/conv_b.
// ---------------------------------------------------------------------------
__global__ __launch_bounds__(256) void precompute_kernel(
    const float* __restrict__ emb, const float* __restrict__ w3,
    const float* __restrict__ b3, const float* __restrict__ root_w,
    const float* __restrict__ conv_b,
    float* __restrict__ W3p, float* __restrict__ b3p, float* __restrict__ r)
{
    int t = blockIdx.x * 256 + threadIdx.x;   // 0..4095
    if (t >= HID * HID) return;
    int k = t >> 6;
    int h = t & 63;
    float acc = 0.f;
#pragma unroll
    for (int i = 0; i < IN_DIM; ++i)
        acc = fmaf(emb[i], w3[k * (IN_DIM * HID) + i * HID + h], acc);
    W3p[t] = acc;
    if (t < HID) {
        float a = 0.f, rr = 0.f;
#pragma unroll
        for (int i = 0; i < IN_DIM; ++i) {
            a  = fmaf(emb[i], b3[i * HID + t], a);
            rr = fmaf(emb[i], root_w[i * HID + t], rr);
        }
        b3p[t] = a;
        r[t]   = rr + conv_b[t];
    }
}

// ---------------------------------------------------------------------------
// Kernel 1: histogram of destination indices.
// ---------------------------------------------------------------------------
__global__ __launch_bounds__(256) void hist_kernel(
    const int* __restrict__ dst_idx, int* __restrict__ counts)
{
    int e = blockIdx.x * 256 + threadIdx.x;
    if (e < N_EDGES) atomicAdd(&counts[dst_idx[e]], 1);
}

// ---------------------------------------------------------------------------
// Kernel 2a/2b/2c: multi-block exclusive scan of counts -> start[]/cursor[].
// ---------------------------------------------------------------------------
__global__ __launch_bounds__(1024) void scanA_kernel(
    const int* __restrict__ counts, int* __restrict__ start, int* __restrict__ tot)
{
    const int b = blockIdx.x, t = threadIdx.x;
    const int i = b * 1024 + t;
    const int v = (i < N_NODES) ? counts[i] : 0;
    const int lane = t & 63, wid = t >> 6;
    __shared__ int wsum[16];
    int incl = v;
#pragma unroll
    for (int off = 1; off < 64; off <<= 1) {
        int u = __shfl_up(incl, off, 64);
        if (lane >= off) incl += u;
    }
    if (lane == 63) wsum[wid] = incl;
    __syncthreads();
    if (wid == 0) {
        int wv = (lane < 16) ? wsum[lane] : 0;
        int wi = wv;
#pragma unroll
        for (int off = 1; off < 16; off <<= 1) {
            int u = __shfl_up(wi, off, 64);
            if (lane >= off) wi += u;
        }
        if (lane < 16) wsum[lane] = wi - wv;   // exclusive wave prefix
    }
    __syncthreads();
    const int excl = wsum[wid] + incl - v;     // block-local exclusive prefix
    if (i < N_NODES) start[i] = excl;
    if (t == 1023) tot[b] = excl + v;          // block total
}

__global__ __launch_bounds__(64) void scanB_kernel(int* __restrict__ tot,
                                                   int* __restrict__ off)
{
    const int t = threadIdx.x;
    int v = (t < SCAN_NBLK) ? tot[t] : 0;
    int incl = v;
#pragma unroll
    for (int o = 1; o < 64; o <<= 1) {
        int u = __shfl_up(incl, o, 64);
        if (t >= o) incl += u;
    }
    if (t < SCAN_NBLK) off[t] = incl - v;      // exclusive
}

__global__ __launch_bounds__(1024) void scanC_kernel(
    int* __restrict__ start, int* __restrict__ cursor, const int* __restrict__ off)
{
    const int b = blockIdx.x, t = threadIdx.x;
    const int i = b * 1024 + t;
    if (i < N_NODES) {
        const int s = start[i] + off[b];
        start[i]  = s;
        cursor[i] = s;
    }
    if (b == 0 && t == 0) start[N_NODES] = N_EDGES;
}

// ---------------------------------------------------------------------------
// Kernel 3: per-edge MLP, transposed: lane j owns output channel j. Weight
// COLUMNS live in VGPRs (loaded once per wave, coalesced); activations are
// broadcast with v_readlane. Inner loop is pure VALU - no LDS/K$/global.
// Each wave processes 64 edges (its lanes' edges), 2 at a time for ILP.
// ---------------------------------------------------------------------------
__global__ __launch_bounds__(256) void edge_kernel(
    const float* __restrict__ edge_attr, const int* __restrict__ dst_idx,
    const float* __restrict__ w1, const float* __restrict__ b1,
    const float* __restrict__ w2, const float* __restrict__ b2,
    const float* __restrict__ W3p, const float* __restrict__ b3p,
    int* __restrict__ cursor, float* __restrict__ msg_buf)
{
    const int lane = threadIdx.x & 63;
    const int wid  = (blockIdx.x * 256 + threadIdx.x) >> 6;  // global wave id
    const long base = (long)wid * 64;
    if (base >= N_EDGES) return;                             // 200000 = 3125*64
    const int j = lane;                                      // output channel

    // ---- per-lane weight columns (coalesced: lane j reads column j) ----
    float w1c[EDGE_DIM], w2c[HID], w3c[HID];
#pragma unroll
    for (int k = 0; k < EDGE_DIM; ++k) w1c[k] = w1[k * HID + j];
#pragma unroll
    for (int k = 0; k < HID; ++k) w2c[k] = w2[k * HID + j];
#pragma unroll
    for (int k = 0; k < HID; ++k) w3c[k] = W3p[k * HID + j];
    const float b1j = b1[j], b2j = b2[j], b3j = b3p[j];

    // ---- my lane's edge: attrs, dst, sorted slot (one atomic instr/wave) --
    const long e_mine = base + lane;
    float ea[EDGE_DIM];
    {
        const float4 a0 = *(const float4*)&edge_attr[e_mine * EDGE_DIM + 0];
        const float4 a1 = *(const float4*)&edge_attr[e_mine * EDGE_DIM + 4];
        ea[0] = a0.x; ea[1] = a0.y; ea[2] = a0.z; ea[3] = a0.w;
        ea[4] = a1.x; ea[5] = a1.y; ea[6] = a1.z; ea[7] = a1.w;
    }
    const int d_mine = dst_idx[e_mine];
    const int p_mine = atomicAdd(&cursor[d_mine], 1);

    // ---- process the wave's 64 edges, 2 at a time ----
#pragma unroll 1
    for (int e = 0; e < 64; e += 2) {
        // L1: h = relu(ea @ w1 + b1)
        float A0 = b1j, A1 = b1j;
#pragma unroll
        for (int k = 0; k < EDGE_DIM; ++k) {
            A0 = fmaf(rlanef(ea[k], e),     w1c[k], A0);
            A1 = fmaf(rlanef(ea[k], e + 1), w1c[k], A1);
        }
        const float H0 = fmaxf(A0, 0.f), H1 = fmaxf(A1, 0.f);

        // L2: g = relu(h @ w2 + b2)
        A0 = b2j; A1 = b2j;
#pragma unroll
        for (int k = 0; k < HID; ++k) {
            A0 = fmaf(rlanef(H0, k), w2c[k], A0);
            A1 = fmaf(rlanef(H1, k), w2c[k], A1);
        }
        const float G0 = fmaxf(A0, 0.f), G1 = fmaxf(A1, 0.f);

        // L3: msg = g @ W3p + b3p
        A0 = b3j; A1 = b3j;
#pragma unroll
        for (int k = 0; k < HID; ++k) {
            A0 = fmaf(rlanef(G0, k), w3c[k], A0);
            A1 = fmaf(rlanef(G1, k), w3c[k], A1);
        }

        // store into dst-sorted slots (coalesced dword per edge)
        const int p0 = __builtin_amdgcn_readlane(p_mine, e);
        const int p1 = __builtin_amdgcn_readlane(p_mine, e + 1);
        msg_buf[(long)p0 * HID + j] = A0;
        msg_buf[(long)p1 * HID + j] = A1;
    }
}

// ---------------------------------------------------------------------------
// Kernel 4: gather msg rows per node, +r, relu, per-graph pooled sums/counts.
// One wave per 8 nodes; lane = hid channel; batch sorted -> run accumulation.
// ---------------------------------------------------------------------------
#define GN_PER_WAVE 8
__global__ __launch_bounds__(256) void gather_kernel(
    const float* __restrict__ msg_buf, const int* __restrict__ start,
    const float* __restrict__ r, const int* __restrict__ batch,
    float* __restrict__ sums, float* __restrict__ counts_f)
{
    const int wave = threadIdx.x >> 6;
    const int j    = threadIdx.x & 63;
    const int n0   = blockIdx.x * (4 * GN_PER_WAVE) + wave * GN_PER_WAVE;
    if (n0 >= N_NODES) return;
    const int n1 = min(n0 + GN_PER_WAVE, N_NODES);
    const float rj = r[j];

    int   g    = batch[n0];
    float pacc = 0.f, cnt = 0.f;
    for (int n = n0; n < n1; ++n) {
        const int gn = batch[n];
        if (gn != g) {
            unsafeAtomicAdd(&sums[g * HID + j], pacc);
            if (j == 0) unsafeAtomicAdd(&counts_f[g], cnt);
            g = gn; pacc = 0.f; cnt = 0.f;
        }
        float acc = 0.f;
        const int p0 = start[n], p1 = start[n + 1];
        for (int p = p0; p < p1; ++p)
            acc += msg_buf[(long)p * HID + j];
        pacc += fmaxf(acc + rj, 0.f);
        cnt  += 1.f;
    }
    unsafeAtomicAdd(&sums[g * HID + j], pacc);
    if (j == 0) unsafeAtomicAdd(&counts_f[g], cnt);
}

// ---------------------------------------------------------------------------
// Kernel 5: classifier head. One block (128 threads) per graph.
// ---------------------------------------------------------------------------
__global__ __launch_bounds__(128) void head_kernel(
    const float* __restrict__ sums, const float* __restrict__ counts,
    const float* __restrict__ l1_w, const float* __restrict__ l1_b,
    const float* __restrict__ l2_w, const float* __restrict__ l2_b,
    float* __restrict__ out)
{
    const int g = blockIdx.x;
    const int t = threadIdx.x;
    __shared__ float pooled[HID];
    __shared__ float hid[2 * HID];

    const float cnt = fmaxf(counts[g], 1.0f);
    if (t < HID) pooled[t] = sums[g * HID + t] / cnt;
    __syncthreads();

    float a = l1_b[t];
#pragma unroll
    for (int k = 0; k < HID; ++k)
        a = fmaf(pooled[k], l1_w[k * (2 * HID) + t], a);
    hid[t] = fmaxf(a, 0.f);
    __syncthreads();

    if (t < OUT_DIM) {
        float o = l2_b[t];
#pragma unroll
        for (int k = 0; k < 2 * HID; ++k)
            o = fmaf(hid[k], l2_w[k * OUT_DIM + t], o);
        out[g * OUT_DIM + t] = o;
    }
}

// ---------------------------------------------------------------------------
extern "C" void kernel_launch(void* const* d_in, const int* in_sizes, int n_in,
                              void* d_out, int out_size, void* d_ws, size_t ws_size,
                              hipStream_t stream) {
    const float* edge_attr = (const float*)d_in[0];
    const int*   edge_idx  = (const int*)d_in[1];
    const int*   batch     = (const int*)d_in[2];
    const float* node_emb  = (const float*)d_in[3];
    const float* w1        = (const float*)d_in[4];
    const float* b1        = (const float*)d_in[5];
    const float* w2        = (const float*)d_in[6];
    const float* b2        = (const float*)d_in[7];
    const float* w3        = (const float*)d_in[8];
    const float* b3        = (const float*)d_in[9];
    const float* root_w    = (const float*)d_in[10];
    const float* conv_b    = (const float*)d_in[11];
    const float* l1_w      = (const float*)d_in[12];
    const float* l1_b      = (const float*)d_in[13];
    const float* l2_w      = (const float*)d_in[14];
    const float* l2_b      = (const float*)d_in[15];
    float* out = (float*)d_out;

    // workspace layout
    float* ws     = (float*)d_ws;
    float* W3p    = ws;                          // 4096
    float* b3p    = W3p + HID * HID;             // 64
    float* r      = b3p + HID;                   // 64
    float* sums   = r + HID;                     // 128*64
    float* cts    = sums + N_GRAPHS * HID;       // 128
    int*   counts = (int*)(cts + N_GRAPHS);      // 20000
    int*   startp = counts + N_NODES;            // 20001
    int*   cursor = startp + (N_NODES + 1);      // 20000
    int*   tot    = cursor + N_NODES;            // 20
    int*   off    = tot + SCAN_NBLK;             // 20
    float* msg    = (float*)(off + SCAN_NBLK);   // 200000*64 floats (51.2 MB)

    // zero sums/cts/counts (contiguous region)
    hipMemsetAsync(sums, 0,
                   (size_t)(N_GRAPHS * HID + N_GRAPHS + N_NODES) * 4, stream);

    precompute_kernel<<<(HID * HID + 255) / 256, 256, 0, stream>>>(
        node_emb, w3, b3, root_w, conv_b, W3p, b3p, r);

    const int* dst_idx = edge_idx + N_EDGES;   // edge_index[1]

    hist_kernel<<<(N_EDGES + 255) / 256, 256, 0, stream>>>(dst_idx, counts);

    scanA_kernel<<<SCAN_NBLK, 1024, 0, stream>>>(counts, startp, tot);
    scanB_kernel<<<1, 64, 0, stream>>>(tot, off);
    scanC_kernel<<<SCAN_NBLK, 1024, 0, stream>>>(startp, cursor, off);

    edge_kernel<<<(N_EDGES / 64 + 3) / 4, 256, 0, stream>>>(
        edge_attr, dst_idx, w1, b1, w2, b2, W3p, b3p, cursor, msg);

    gather_kernel<<<(N_NODES + 4 * GN_PER_WAVE - 1) / (4 * GN_PER_WAVE), 256, 0, stream>>>(
        msg, startp, r, batch, sums, cts);

    head_kernel<<<N_GRAPHS, 128, 0, stream>>>(
        sums, cts, l1_w, l1_b, l2_w, l2_b, out);
}